// Round 7
// baseline (236.247 us; speedup 1.0000x reference)
//
#include <hip/hip_runtime.h>
#include <math.h>

typedef __attribute__((ext_vector_type(4))) float f32x4;
typedef __attribute__((ext_vector_type(8))) short s16x8;

// small-GEMM tile
#define BM 32
#define BN 256
#define BK 64
#define LDS_TILE ((BM + BN) * BK)

// big-GEMM tile
#define BM2 64
#define BN2 256
#define BK2 64
#define KFULL 8192
#define ZSPLIT 2
#define KQ (KFULL / ZSPLIT)       // 4096
#define BUFHW ((BM2 + BN2) * BK2) // 20480 halfwords per buffer
#define DVHW (3 * BUFHW)          // dinv table offset (halfwords)

__device__ __forceinline__ unsigned short f2bf(float f) {
  unsigned int u = __float_as_uint(f);
  u += 0x7fffu + ((u >> 16) & 1u);
  return (unsigned short)(u >> 16);
}
__device__ __forceinline__ float bf2f(unsigned short h) {
  unsigned int u = ((unsigned int)h) << 16;
  return __uint_as_float(u);
}

__device__ __forceinline__ void gload16(const void* g, void* l) {
  __builtin_amdgcn_global_load_lds(
      (const __attribute__((address_space(1))) void*)g,
      (__attribute__((address_space(3))) void*)l, 16, 0, 0);
}

// ---------------- merged weight transposes: W[K][M] -> WT[M][K] fp32 ----------------
__global__ __launch_bounds__(256) void transW(const float* __restrict__ W1,
                                              const float* __restrict__ W2,
                                              float* __restrict__ W1T,
                                              float* __restrict__ W2T) {
  __shared__ float t[64][65];
  int bx = blockIdx.x;
  const float* in;
  float* out;
  int K, M;
  if (bx < 32) { in = W1; out = W1T; K = 512; M = 256; }
  else { bx -= 32; in = W2; out = W2T; K = 256; M = 256; }
  int tiles_m = M >> 6;
  int tk = bx / tiles_m, tm = bx % tiles_m;
  int k0 = tk * 64, m0 = tm * 64;
  int ty = threadIdx.x >> 4, tx = threadIdx.x & 15;
#pragma unroll
  for (int i = 0; i < 4; ++i) {
    f32x4 v = *(const f32x4*)(in + (size_t)(k0 + ty + 16 * i) * M + m0 + tx * 4);
    t[ty + 16 * i][tx * 4 + 0] = v[0];
    t[ty + 16 * i][tx * 4 + 1] = v[1];
    t[ty + 16 * i][tx * 4 + 2] = v[2];
    t[ty + 16 * i][tx * 4 + 3] = v[3];
  }
  __syncthreads();
#pragma unroll
  for (int i = 0; i < 4; ++i) {
    int m = ty + 16 * i;
    f32x4 v = {t[tx * 4 + 0][m], t[tx * 4 + 1][m], t[tx * 4 + 2][m], t[tx * 4 + 3][m]};
    *(f32x4*)(out + (size_t)(m0 + m) * K + k0 + tx * 4) = v;
  }
}

// ---------------- small GEMM: C[M,N] = AT[M,K] * BT[N,K]^T ----------------
// EPI 3: bf16 out = acc + bias[row]             (gemm3: h1, no dinv yet)
// EPI 1: bf16 out = (acc + bias[row])*dinv[col] (gemm6 -> hs2T)
template <bool BF32, int EPI>
__device__ __forceinline__ void gemm_small(int bx, unsigned short* ldsb,
                                           const float* __restrict__ AT,
                                           const void* __restrict__ BTp,
                                           void* __restrict__ outp,
                                           const float* __restrict__ bias,
                                           const float* __restrict__ dinv,
                                           int M, int N, int K) {
  const int tid = threadIdx.x;
  const int m0 = (bx & (M / BM - 1)) * BM;
  const int n0 = (bx / (M / BM)) * BN;
  const int sr = tid >> 3;
  const int sc = (tid & 7) * 8;
  const float* Bf = (const float*)BTp;
  const unsigned short* Bh = (const unsigned short*)BTp;

  f32x4 a_f[2];
  f32x4 b_f[8][2];
  s16x8 b_h[8];

  auto stage_load = [&](int k0) {
    const float* pa = AT + (size_t)(m0 + sr) * K + k0 + sc;
    a_f[0] = *(const f32x4*)(pa);
    a_f[1] = *(const f32x4*)(pa + 4);
#pragma unroll
    for (int it = 0; it < 8; ++it) {
      int n = n0 + it * 32 + sr;
      if (BF32) {
        const float* p = Bf + (size_t)n * K + k0 + sc;
        b_f[it][0] = *(const f32x4*)(p);
        b_f[it][1] = *(const f32x4*)(p + 4);
      } else {
        b_h[it] = *(const s16x8*)(Bh + (size_t)n * K + k0 + sc);
      }
    }
  };

  auto stage_write = [&](int buf) {
    unsigned short* L = ldsb + buf * LDS_TILE;
    {
      s16x8 v;
#pragma unroll
      for (int j = 0; j < 8; ++j) v[j] = (short)f2bf(j < 4 ? a_f[0][j] : a_f[1][j - 4]);
      int idx = (sr * BK + sc) ^ ((sr & 7) << 3);
      *(s16x8*)(L + idx) = v;
    }
#pragma unroll
    for (int it = 0; it < 8; ++it) {
      int r = it * 32 + sr;
      s16x8 w;
      if (BF32) {
#pragma unroll
        for (int j = 0; j < 8; ++j)
          w[j] = (short)f2bf(j < 4 ? b_f[it][0][j] : b_f[it][1][j - 4]);
      } else {
        w = b_h[it];
      }
      int idx = BM * BK + ((r * BK + sc) ^ ((r & 7) << 3));
      *(s16x8*)(L + idx) = w;
    }
  };

  const int lane = tid & 63;
  const int wv = tid >> 6;
  const int g = lane >> 4, lr = lane & 15;

  int aidx[2][2], bidx[4][2];
#pragma unroll
  for (int m = 0; m < 2; ++m)
#pragma unroll
    for (int ks = 0; ks < 2; ++ks) {
      int r = m * 16 + lr;
      aidx[m][ks] = (r * BK + ks * 32 + g * 8) ^ ((r & 7) << 3);
    }
#pragma unroll
  for (int n = 0; n < 4; ++n)
#pragma unroll
    for (int ks = 0; ks < 2; ++ks) {
      int r = wv * 64 + n * 16 + lr;
      bidx[n][ks] = BM * BK + ((r * BK + ks * 32 + g * 8) ^ ((r & 7) << 3));
    }

  f32x4 acc[2][4];
#pragma unroll
  for (int m = 0; m < 2; ++m)
#pragma unroll
    for (int n = 0; n < 4; ++n) {
      f32x4 z = {0.f, 0.f, 0.f, 0.f};
      acc[m][n] = z;
    }

  auto compute = [&](int buf) {
    const unsigned short* L = ldsb + buf * LDS_TILE;
    s16x8 af[2][2], bfr[4][2];
#pragma unroll
    for (int m = 0; m < 2; ++m)
#pragma unroll
      for (int ks = 0; ks < 2; ++ks) af[m][ks] = *(const s16x8*)(L + aidx[m][ks]);
#pragma unroll
    for (int n = 0; n < 4; ++n)
#pragma unroll
      for (int ks = 0; ks < 2; ++ks) bfr[n][ks] = *(const s16x8*)(L + bidx[n][ks]);
#pragma unroll
    for (int m = 0; m < 2; ++m)
#pragma unroll
      for (int n = 0; n < 4; ++n)
#pragma unroll
        for (int ks = 0; ks < 2; ++ks)
          acc[m][n] = __builtin_amdgcn_mfma_f32_16x16x32_bf16(af[m][ks], bfr[n][ks],
                                                              acc[m][n], 0, 0, 0);
  };

  stage_load(0);
  stage_write(0);
  __syncthreads();
  int cur = 0;
  const int nt = K / BK;
  for (int t = 0; t < nt; ++t) {
    if (t + 1 < nt) stage_load((t + 1) * BK);
    compute(cur);
    if (t + 1 < nt) {
      stage_write(cur ^ 1);
      __syncthreads();
      cur ^= 1;
    }
  }

#pragma unroll
  for (int m = 0; m < 2; ++m)
#pragma unroll
    for (int n = 0; n < 4; ++n) {
      int col = n0 + wv * 64 + n * 16 + lr;
#pragma unroll
      for (int r = 0; r < 4; ++r) {
        int row = m0 + m * 16 + g * 4 + r;
        float v = acc[m][n][r];
        if constexpr (EPI == 3) {
          ((unsigned short*)outp)[(size_t)row * N + col] = f2bf(v + bias[row]);
        } else {
          ((unsigned short*)outp)[(size_t)row * N + col] = f2bf((v + bias[row]) * dinv[col]);
        }
      }
    }
}

// ---------------- prep: gemm3 blocks [0,256) + adj conv/rowsum blocks [256,4352) ----------------
__global__ __launch_bounds__(256) void prep(const float* __restrict__ adj,
                                            const float* __restrict__ x,
                                            const float* __restrict__ W1T,
                                            const float* __restrict__ b1,
                                            unsigned short* __restrict__ adjh,
                                            float* __restrict__ dinv,
                                            unsigned short* __restrict__ h1) {
  __shared__ unsigned short lds[2 * LDS_TILE];
  int bx = blockIdx.x;
  if (bx < 256) {
    gemm_small<true, 3>(bx, lds, W1T, x, h1, b1, nullptr, 256, 8192, 512);
    return;
  }
  bx -= 256;
  float* smf = (float*)lds;
  const int tid = threadIdx.x;
  float psum[2];
#pragma unroll
  for (int rr = 0; rr < 2; ++rr) {
    int row = bx * 2 + rr;
    const float* src = adj + (size_t)row * 8192;
    unsigned short* dst = adjh + (size_t)row * 8192;
    float s = 0.f;
    for (int c = tid * 8; c < 8192; c += 2048) {
      f32x4 v0 = __builtin_nontemporal_load((const f32x4*)(src + c));
      f32x4 v1 = __builtin_nontemporal_load((const f32x4*)(src + c + 4));
      s += v0[0] + v0[1] + v0[2] + v0[3] + v1[0] + v1[1] + v1[2] + v1[3];
      if (row >= c && row < c + 8) {  // identity added AFTER summing (deg = rowsum+1)
        int d = row - c;
        if (d < 4) v0[d] += 1.f; else v1[d - 4] += 1.f;
      }
      s16x8 o;
#pragma unroll
      for (int j = 0; j < 4; ++j) {
        o[j] = (short)f2bf(v0[j]);
        o[j + 4] = (short)f2bf(v1[j]);
      }
      *(s16x8*)(dst + c) = o;
    }
    psum[rr] = s;
  }
#pragma unroll
  for (int rr = 0; rr < 2; ++rr) {
    float s = psum[rr];
#pragma unroll
    for (int off = 32; off > 0; off >>= 1) s += __shfl_down(s, off, 64);
    if ((tid & 63) == 0) smf[rr * 4 + (tid >> 6)] = s;
  }
  __syncthreads();
  if (tid < 2) {
    float tot = smf[tid * 4] + smf[tid * 4 + 1] + smf[tid * 4 + 2] + smf[tid * 4 + 3];
    dinv[bx * 2 + tid] = rsqrtf(tot + 1.0f);
  }
}

// ---------------- big GEMM (split-K=2): P[z] = adjh @ B^T partials ----------------
// BM2=64, NBUF=3, ONE barrier per K-step, counted vmcnt(5), stage 2 iters ahead.
// SCALEB: B = h1 (unscaled), reg-staged (brA/brB ping-pong) with dinv from LDS table.
// !SCALEB: B = hs2T (pre-scaled), pure global_load_lds staging.
template <bool SCALEB>
__global__ __launch_bounds__(512) void gemm_big(const unsigned short* __restrict__ A,
                                                const unsigned short* __restrict__ B,
                                                const float* __restrict__ dinv,
                                                float* __restrict__ P) {
  __shared__ unsigned short lds[3 * BUFHW + (SCALEB ? 8192 : 0)];  // 120/136 KB
  float* DV = (float*)(lds + DVHW);
  const int tid = threadIdx.x;
  const int mt = blockIdx.x & 127;
  const int z = blockIdx.x >> 7;
  const int m0 = mt * BM2;

  const int l = tid & 63;
  const int ra = tid >> 3, col8 = tid & 7;
  const int swz = (col8 * 16) ^ ((ra & 7) << 4);  // byte offset, matches read XOR

  // A: 1 gload16/thread/step; dest linear = L + tid*8 (hw)
  const char* Asrc = (const char*)(A + (size_t)(m0 + ra) * KFULL + (size_t)z * KQ) + swz;
  auto stageA = [&](int buf, int t) {
    gload16(Asrc + (size_t)t * (BK2 * 2), lds + buf * BUFHW + tid * 8);
  };

  // B: 4 gload16 (or reg loads) /thread/step
  const int sr = tid >> 3, sc = (tid & 7) * 8;
  const char* Bsrc[4];
#pragma unroll
  for (int j = 0; j < 4; ++j) {
    if (SCALEB)
      Bsrc[j] = (const char*)(B + (size_t)(sr + 64 * j) * KFULL + (size_t)z * KQ + sc);
    else
      Bsrc[j] = (const char*)(B + (size_t)(j * 64 + ra) * KFULL + (size_t)z * KQ) + swz;
  }
  auto loadB = [&](s16x8 (&br)[4], int t) {
#pragma unroll
    for (int j = 0; j < 4; ++j)
      br[j] = *(const s16x8*)(Bsrc[j] + (size_t)t * (BK2 * 2));
  };
  auto writeB = [&](int buf, int t, const s16x8 (&br)[4]) {
    unsigned short* L = lds + buf * BUFHW + BM2 * BK2;
    f32x4 d0 = *(const f32x4*)(DV + t * 64 + sc);
    f32x4 d1 = *(const f32x4*)(DV + t * 64 + sc + 4);
#pragma unroll
    for (int j = 0; j < 4; ++j) {
      int r = sr + 64 * j;
      s16x8 o;
#pragma unroll
      for (int e = 0; e < 4; ++e) {
        o[e] = (short)f2bf(bf2f((unsigned short)br[j][e]) * d0[e]);
        o[e + 4] = (short)f2bf(bf2f((unsigned short)br[j][e + 4]) * d1[e]);
      }
      *(s16x8*)(L + ((r * 64 + sc) ^ ((r & 7) << 3))) = o;
    }
  };
  auto stageB_dma = [&](int buf, int t) {
    unsigned short* L = lds + buf * BUFHW + BM2 * BK2;
#pragma unroll
    for (int j = 0; j < 4; ++j)
      gload16(Bsrc[j] + (size_t)t * (BK2 * 2), L + j * 4096 + tid * 8);
  };

  const int w = tid >> 6;
  const int wr = w >> 2, wc = w & 3;     // 2 row-halves x 4 col-quarters
  const int g = l >> 4, lr = l & 15;
  int aidx[2][2], bidx[4][2];
#pragma unroll
  for (int m = 0; m < 2; ++m)
#pragma unroll
    for (int ks = 0; ks < 2; ++ks) {
      int r = wr * 32 + m * 16 + lr;
      aidx[m][ks] = r * 64 + ((ks * 32 + g * 8) ^ ((r & 7) << 3));
    }
#pragma unroll
  for (int n = 0; n < 4; ++n)
#pragma unroll
    for (int ks = 0; ks < 2; ++ks) {
      int r = wc * 64 + n * 16 + lr;
      bidx[n][ks] = BM2 * BK2 + r * 64 + ((ks * 32 + g * 8) ^ ((r & 7) << 3));
    }

  f32x4 acc[2][4];
#pragma unroll
  for (int m = 0; m < 2; ++m)
#pragma unroll
    for (int n = 0; n < 4; ++n) {
      f32x4 zz = {0.f, 0.f, 0.f, 0.f};
      acc[m][n] = zz;
    }

  s16x8 brA[4], brB[4];

  // ---- prologue: tiles 0 and 1 staged ----
  if (SCALEB) {
    f32x4 dv0 = *(const f32x4*)(dinv + (size_t)z * KQ + tid * 8);
    f32x4 dv1 = *(const f32x4*)(dinv + (size_t)z * KQ + tid * 8 + 4);
    *(f32x4*)(DV + tid * 8) = dv0;
    *(f32x4*)(DV + tid * 8 + 4) = dv1;
  }
  stageA(0, 0);
  stageA(1, 1);
  if (SCALEB) { loadB(brA, 0); loadB(brB, 1); }
  else { stageB_dma(0, 0); stageB_dma(1, 1); }
  __syncthreads();  // drains everything; DV visible
  if (SCALEB) { writeB(0, 0, brA); writeB(1, 1, brB); }

  const int nt = KQ / BK2;  // 64
  auto body = [&](int t, s16x8 (&brLoad)[4], s16x8 (&brWrite)[4]) {
    int cur = t % 3;
    if (t + 1 < nt) asm volatile("s_waitcnt vmcnt(5)" ::: "memory");
    else            asm volatile("s_waitcnt vmcnt(0)" ::: "memory");
    asm volatile("s_waitcnt lgkmcnt(0)" ::: "memory");
    asm volatile("s_barrier" ::: "memory");
    __builtin_amdgcn_sched_barrier(0);

    const unsigned short* L = lds + cur * BUFHW;
    s16x8 af[2][2], bfr[4][2];
#pragma unroll
    for (int m = 0; m < 2; ++m)
#pragma unroll
      for (int ks = 0; ks < 2; ++ks) af[m][ks] = *(const s16x8*)(L + aidx[m][ks]);
#pragma unroll
    for (int n = 0; n < 4; ++n)
#pragma unroll
      for (int ks = 0; ks < 2; ++ks) bfr[n][ks] = *(const s16x8*)(L + bidx[n][ks]);

    if (t + 2 < nt) {
      int nb = (t + 2) % 3;
      stageA(nb, t + 2);
      if (SCALEB) loadB(brLoad, t + 2);
      else stageB_dma(nb, t + 2);
    }

    __builtin_amdgcn_s_setprio(1);
#pragma unroll
    for (int m = 0; m < 2; ++m)
#pragma unroll
      for (int n = 0; n < 4; ++n)
#pragma unroll
        for (int ks = 0; ks < 2; ++ks)
          acc[m][n] = __builtin_amdgcn_mfma_f32_16x16x32_bf16(af[m][ks], bfr[n][ks],
                                                              acc[m][n], 0, 0, 0);
    __builtin_amdgcn_s_setprio(0);

    if (SCALEB && t > 0 && t + 1 < nt) writeB((t + 1) % 3, t + 1, brWrite);
  };
  for (int t = 0; t < nt; t += 2) {
    body(t, brA, brB);       // loads B(t+2) into brA; writes B(t+1) from brB
    body(t + 1, brB, brA);   // loads B(t+3) into brB; writes B(t+2) from brA
  }

  float* Pz = P + (size_t)z * 8192 * 256;
#pragma unroll
  for (int m = 0; m < 2; ++m)
#pragma unroll
    for (int n = 0; n < 4; ++n) {
      int col = wc * 64 + n * 16 + lr;
#pragma unroll
      for (int r = 0; r < 4; ++r) {
        int row = m0 + wr * 32 + m * 16 + g * 4 + r;
        Pz[(size_t)row * 256 + col] = acc[m][n][r];
      }
    }
}

// ---------------- reduce1: hln = LN(GELU((P0+P1)*dinv[row])), bf16 out ----------------
__global__ __launch_bounds__(256) void reduce_ln(const float* __restrict__ P,
                                                 const float* __restrict__ dinv,
                                                 const float* __restrict__ gamma,
                                                 const float* __restrict__ beta,
                                                 unsigned short* __restrict__ hln) {
  const size_t ZSTR = (size_t)8192 * 256;
  int row = blockIdx.x * 4 + (threadIdx.x >> 6);
  int l = threadIdx.x & 63;
  const float* p = P + (size_t)row * 256 + l * 4;
  f32x4 a = *(const f32x4*)p;
  f32x4 b = *(const f32x4*)(p + ZSTR);
  float di = dinv[row];
  float gl[4];
  float s = 0.f, q = 0.f;
#pragma unroll
  for (int j = 0; j < 4; ++j) {
    float v = (a[j] + b[j]) * di;
    float gv = 0.5f * v * (1.0f + erff(v * 0.70710678118654752440f));
    gl[j] = gv;
    s += gv;
    q += gv * gv;
  }
#pragma unroll
  for (int off = 1; off < 64; off <<= 1) {
    s += __shfl_xor(s, off, 64);
    q += __shfl_xor(q, off, 64);
  }
  float mu = s * (1.0f / 256.0f);
  float var = q * (1.0f / 256.0f) - mu * mu;
  float rs = rsqrtf(fmaxf(var, 0.f) + 1e-6f);
  f32x4 gm = *(const f32x4*)(gamma + l * 4);
  f32x4 bt = *(const f32x4*)(beta + l * 4);
  unsigned short o4[4];
#pragma unroll
  for (int j = 0; j < 4; ++j)
    o4[j] = f2bf((gl[j] - mu) * rs * gm[j] + bt[j]);
  *(unsigned long long*)(hln + (size_t)row * 256 + l * 4) =
      *(const unsigned long long*)o4;
}

// ---------------- reduce2: out fp32 = (P0+P1)*dinv[row] ----------------
__global__ __launch_bounds__(256) void reduce_sc(const float* __restrict__ P,
                                                 const float* __restrict__ dinv,
                                                 float* __restrict__ out) {
  const size_t ZSTR = (size_t)8192 * 256;
  size_t i = ((size_t)blockIdx.x * 256 + threadIdx.x) * 4;
  int row = (int)(i >> 8);
  f32x4 a = *(const f32x4*)(P + i);
  f32x4 b = *(const f32x4*)(P + ZSTR + i);
  float di = dinv[row];
  f32x4 o;
#pragma unroll
  for (int j = 0; j < 4; ++j) o[j] = (a[j] + b[j]) * di;
  *(f32x4*)(out + i) = o;
}

// ---------------- GEMM6: hs2T = bf16((hln @ W2 + b2)^T * dinv[col]) ----------------
__global__ __launch_bounds__(256) void gemm6_k(const float* __restrict__ W2T,
                                               const unsigned short* __restrict__ hln,
                                               unsigned short* __restrict__ hs2T,
                                               const float* __restrict__ b2,
                                               const float* __restrict__ dinv) {
  __shared__ unsigned short lds[2 * LDS_TILE];
  gemm_small<false, 1>(blockIdx.x, lds, W2T, hln, hs2T, b2, dinv, 256, 8192, 256);
}

// ---------------- launch ----------------
extern "C" void kernel_launch(void* const* d_in, const int* in_sizes, int n_in,
                              void* d_out, int out_size, void* d_ws, size_t ws_size,
                              hipStream_t stream) {
  (void)in_sizes; (void)n_in; (void)out_size; (void)ws_size;
  const float* x     = (const float*)d_in[0];
  const float* adj   = (const float*)d_in[1];
  const float* W1    = (const float*)d_in[2];
  const float* b1    = (const float*)d_in[3];
  const float* W2    = (const float*)d_in[4];
  const float* b2    = (const float*)d_in[5];
  const float* gamma = (const float*)d_in[6];
  const float* beta  = (const float*)d_in[7];
  float* out = (float*)d_out;

  char* ws = (char*)d_ws;
  float* dinv          = (float*)ws;                           // 32 KB
  float* W1T           = (float*)(ws + (64 << 10));            // 512 KB [256][512]
  float* W2T           = (float*)(ws + (640 << 10));           // 256 KB [256][256]
  unsigned short* h1   = (unsigned short*)(ws + (1 << 20));    // 4 MB [256][8192] (pre-dinv)
  unsigned short* hln  = (unsigned short*)(ws + (16 << 20));   // 4 MB [8192][256]
  unsigned short* hs2T = (unsigned short*)(ws + (24 << 20));   // 4 MB [256][8192]
  float* P             = (float*)(ws + (32 << 20));            // 16 MB [2][8192][256]
  unsigned short* adjh = (unsigned short*)(ws + (64 << 20));   // 128 MB [8192][8192] (adj+I)

  // 0) weight transposes (merged)
  transW<<<48, 256, 0, stream>>>(W1, W2, W1T, W2T);
  // 1) gemm3 (h1 bf16) + adj->bf16(+I) + rowsum->dinv, fused
  prep<<<4352, 256, 0, stream>>>(adj, x, W1T, b1, adjh, dinv, h1);
  // 2) P = split-K=2 partials of (adj+I) @ (h1*dinv)  [dinv fused into B staging]
  gemm_big<true><<<256, 512, 0, stream>>>(adjh, h1, dinv, P);
  // 3) hln = LN(GELU((P0+P1)*dinv[row]))
  reduce_ln<<<2048, 256, 0, stream>>>(P, dinv, gamma, beta, hln);
  // 4) hs2T = bf16((hln @ W2 + b2)^T * dinv[node])
  gemm6_k<<<256, 256, 0, stream>>>(W2T, hln, hs2T, b2, dinv);
  // 5) P = split-K=2 partials of (adj+I) @ hs2
  gemm_big<false><<<256, 512, 0, stream>>>(adjh, hs2T, dinv, P);
  // 6) out = (P0+P1)*dinv[row]
  reduce_sc<<<2048, 256, 0, stream>>>(P, dinv, out);
}

// Round 9
// 177.665 us; speedup vs baseline: 1.3297x; 1.3297x over previous
//
#include <hip/hip_runtime.h>
#include <math.h>

typedef __attribute__((ext_vector_type(4))) float f32x4;
typedef __attribute__((ext_vector_type(8))) short s16x8;
typedef __attribute__((ext_vector_type(2))) int i32x2;
typedef __attribute__((ext_vector_type(4))) int i32x4;

// small-GEMM tile
#define BM 32
#define BN 256
#define BK 64
#define LDS_TILE ((BM + BN) * BK)

// big-GEMM tile (int8)
#define BM2 128
#define BN2 256
#define BK2 128              // elements = bytes per row-chunk
#define KFULL 8192
#define ZSPLIT 4
#define KQ (KFULL / ZSPLIT)  // 2048
#define ABYTES (BM2 * BK2)   // 16384
#define BBYTES (BN2 * BK2)   // 32768
#define BUFB (ABYTES + BBYTES)  // 49152 bytes per buffer

#define SHS 2048.0f
#define INVQ (1.0f / (127.0f * 2048.0f))
#define INVSHS (1.0f / 2048.0f)

__device__ __forceinline__ unsigned short f2bf(float f) {
  unsigned int u = __float_as_uint(f);
  u += 0x7fffu + ((u >> 16) & 1u);
  return (unsigned short)(u >> 16);
}
__device__ __forceinline__ float bf2f(unsigned short h) {
  unsigned int u = ((unsigned int)h) << 16;
  return __uint_as_float(u);
}
// round-to-nearest-even float->int for |x| < 2^22 (magic-add trick)
__device__ __forceinline__ int rne_i(float x) {
  return __float_as_int(x + 12582912.0f) - 0x4B400000;
}
__device__ __forceinline__ int q_hs(float v) {
  int q = rne_i(v * SHS);
  return q < -127 ? -127 : (q > 127 ? 127 : q);
}
__device__ __forceinline__ void gload16(const void* g, void* l) {
  __builtin_amdgcn_global_load_lds(
      (const __attribute__((address_space(1))) void*)g,
      (__attribute__((address_space(3))) void*)l, 16, 0, 0);
}

// ---------------- merged weight transposes: W[K][M] -> WT[M][K] fp32 ----------------
__global__ __launch_bounds__(256) void transW(const float* __restrict__ W1,
                                              const float* __restrict__ W2,
                                              float* __restrict__ W1T,
                                              float* __restrict__ W2T) {
  __shared__ float t[64][65];
  int bx = blockIdx.x;
  const float* in;
  float* out;
  int K, M;
  if (bx < 32) { in = W1; out = W1T; K = 512; M = 256; }
  else { bx -= 32; in = W2; out = W2T; K = 256; M = 256; }
  int tiles_m = M >> 6;
  int tk = bx / tiles_m, tm = bx % tiles_m;
  int k0 = tk * 64, m0 = tm * 64;
  int ty = threadIdx.x >> 4, tx = threadIdx.x & 15;
#pragma unroll
  for (int i = 0; i < 4; ++i) {
    f32x4 v = *(const f32x4*)(in + (size_t)(k0 + ty + 16 * i) * M + m0 + tx * 4);
    t[ty + 16 * i][tx * 4 + 0] = v[0];
    t[ty + 16 * i][tx * 4 + 1] = v[1];
    t[ty + 16 * i][tx * 4 + 2] = v[2];
    t[ty + 16 * i][tx * 4 + 3] = v[3];
  }
  __syncthreads();
#pragma unroll
  for (int i = 0; i < 4; ++i) {
    int m = ty + 16 * i;
    f32x4 v = {t[tx * 4 + 0][m], t[tx * 4 + 1][m], t[tx * 4 + 2][m], t[tx * 4 + 3][m]};
    *(f32x4*)(out + (size_t)(m0 + m) * K + k0 + tx * 4) = v;
  }
}

// ---------------- small GEMM (bf16 MFMA): C[M,N] = AT[M,K] * BT[N,K]^T ----------------
// EPI 3: bf16 out = acc + bias[row]                        (gemm3 -> h1)
// EPI 6: int8 out = clamp(rne((acc+bias[row])*dinv[col]*2048)) (gemm6 -> hq2)
template <bool BF32, int EPI>
__device__ __forceinline__ void gemm_small(int bx, unsigned short* ldsb,
                                           const float* __restrict__ AT,
                                           const void* __restrict__ BTp,
                                           void* __restrict__ outp,
                                           const float* __restrict__ bias,
                                           const float* __restrict__ dinv,
                                           int M, int N, int K) {
  const int tid = threadIdx.x;
  const int m0 = (bx & (M / BM - 1)) * BM;
  const int n0 = (bx / (M / BM)) * BN;
  const int sr = tid >> 3;
  const int sc = (tid & 7) * 8;
  const float* Bf = (const float*)BTp;
  const unsigned short* Bh = (const unsigned short*)BTp;

  f32x4 a_f[2];
  f32x4 b_f[8][2];
  s16x8 b_h[8];

  auto stage_load = [&](int k0) {
    const float* pa = AT + (size_t)(m0 + sr) * K + k0 + sc;
    a_f[0] = *(const f32x4*)(pa);
    a_f[1] = *(const f32x4*)(pa + 4);
#pragma unroll
    for (int it = 0; it < 8; ++it) {
      int n = n0 + it * 32 + sr;
      if (BF32) {
        const float* p = Bf + (size_t)n * K + k0 + sc;
        b_f[it][0] = *(const f32x4*)(p);
        b_f[it][1] = *(const f32x4*)(p + 4);
      } else {
        b_h[it] = *(const s16x8*)(Bh + (size_t)n * K + k0 + sc);
      }
    }
  };

  auto stage_write = [&](int buf) {
    unsigned short* L = ldsb + buf * LDS_TILE;
    {
      s16x8 v;
#pragma unroll
      for (int j = 0; j < 8; ++j) v[j] = (short)f2bf(j < 4 ? a_f[0][j] : a_f[1][j - 4]);
      int idx = (sr * BK + sc) ^ ((sr & 7) << 3);
      *(s16x8*)(L + idx) = v;
    }
#pragma unroll
    for (int it = 0; it < 8; ++it) {
      int r = it * 32 + sr;
      s16x8 w;
      if (BF32) {
#pragma unroll
        for (int j = 0; j < 8; ++j)
          w[j] = (short)f2bf(j < 4 ? b_f[it][0][j] : b_f[it][1][j - 4]);
      } else {
        w = b_h[it];
      }
      int idx = BM * BK + ((r * BK + sc) ^ ((r & 7) << 3));
      *(s16x8*)(L + idx) = w;
    }
  };

  const int lane = tid & 63;
  const int wv = tid >> 6;
  const int g = lane >> 4, lr = lane & 15;

  int aidx[2][2], bidx[4][2];
#pragma unroll
  for (int m = 0; m < 2; ++m)
#pragma unroll
    for (int ks = 0; ks < 2; ++ks) {
      int r = m * 16 + lr;
      aidx[m][ks] = (r * BK + ks * 32 + g * 8) ^ ((r & 7) << 3);
    }
#pragma unroll
  for (int n = 0; n < 4; ++n)
#pragma unroll
    for (int ks = 0; ks < 2; ++ks) {
      int r = wv * 64 + n * 16 + lr;
      bidx[n][ks] = BM * BK + ((r * BK + ks * 32 + g * 8) ^ ((r & 7) << 3));
    }

  f32x4 acc[2][4];
#pragma unroll
  for (int m = 0; m < 2; ++m)
#pragma unroll
    for (int n = 0; n < 4; ++n) {
      f32x4 z = {0.f, 0.f, 0.f, 0.f};
      acc[m][n] = z;
    }

  auto compute = [&](int buf) {
    const unsigned short* L = ldsb + buf * LDS_TILE;
    s16x8 af[2][2], bfr[4][2];
#pragma unroll
    for (int m = 0; m < 2; ++m)
#pragma unroll
      for (int ks = 0; ks < 2; ++ks) af[m][ks] = *(const s16x8*)(L + aidx[m][ks]);
#pragma unroll
    for (int n = 0; n < 4; ++n)
#pragma unroll
      for (int ks = 0; ks < 2; ++ks) bfr[n][ks] = *(const s16x8*)(L + bidx[n][ks]);
#pragma unroll
    for (int m = 0; m < 2; ++m)
#pragma unroll
      for (int n = 0; n < 4; ++n)
#pragma unroll
        for (int ks = 0; ks < 2; ++ks)
          acc[m][n] = __builtin_amdgcn_mfma_f32_16x16x32_bf16(af[m][ks], bfr[n][ks],
                                                              acc[m][n], 0, 0, 0);
  };

  stage_load(0);
  stage_write(0);
  __syncthreads();
  int cur = 0;
  const int nt = K / BK;
  for (int t = 0; t < nt; ++t) {
    if (t + 1 < nt) stage_load((t + 1) * BK);
    compute(cur);
    if (t + 1 < nt) {
      stage_write(cur ^ 1);
      __syncthreads();
      cur ^= 1;
    }
  }

#pragma unroll
  for (int m = 0; m < 2; ++m)
#pragma unroll
    for (int n = 0; n < 4; ++n) {
      int col = n0 + wv * 64 + n * 16 + lr;
#pragma unroll
      for (int r = 0; r < 4; ++r) {
        int row = m0 + m * 16 + g * 4 + r;
        float v = acc[m][n][r];
        if constexpr (EPI == 3) {
          ((unsigned short*)outp)[(size_t)row * N + col] = f2bf(v + bias[row]);
        } else {
          int q = q_hs((v + bias[row]) * dinv[col]);
          ((char*)outp)[(size_t)row * N + col] = (char)q;
        }
      }
    }
}

// ---------------- prep: gemm3 blocks [0,256) + adj conv/rowsum blocks [256,4352) ----------------
__global__ __launch_bounds__(256) void prep(const float* __restrict__ adj,
                                            const float* __restrict__ x,
                                            const float* __restrict__ W1T,
                                            const float* __restrict__ b1,
                                            char* __restrict__ adjq,
                                            float* __restrict__ dinv,
                                            unsigned short* __restrict__ h1) {
  __shared__ unsigned short lds[2 * LDS_TILE];
  int bx = blockIdx.x;
  if (bx < 256) {
    gemm_small<true, 3>(bx, lds, W1T, x, h1, b1, nullptr, 256, 8192, 512);
    return;
  }
  bx -= 256;
  float* smf = (float*)lds;
  const int tid = threadIdx.x;
  float psum[2];
#pragma unroll
  for (int rr = 0; rr < 2; ++rr) {
    int row = bx * 2 + rr;
    const float* src = adj + (size_t)row * 8192;
    char* dst = adjq + (size_t)row * 8192;
    float s = 0.f;
    for (int c = tid * 8; c < 8192; c += 2048) {
      f32x4 v0 = __builtin_nontemporal_load((const f32x4*)(src + c));
      f32x4 v1 = __builtin_nontemporal_load((const f32x4*)(src + c + 4));
      s += v0[0] + v0[1] + v0[2] + v0[3] + v1[0] + v1[1] + v1[2] + v1[3];
      // no +I fold: identity term added exactly in the reduce kernels
      i32x2 o;
      o[0] = (rne_i(v0[0] * 127.f) & 0xff) | ((rne_i(v0[1] * 127.f) & 0xff) << 8) |
             ((rne_i(v0[2] * 127.f) & 0xff) << 16) | (rne_i(v0[3] * 127.f) << 24);
      o[1] = (rne_i(v1[0] * 127.f) & 0xff) | ((rne_i(v1[1] * 127.f) & 0xff) << 8) |
             ((rne_i(v1[2] * 127.f) & 0xff) << 16) | (rne_i(v1[3] * 127.f) << 24);
      *(i32x2*)(dst + c) = o;
    }
    psum[rr] = s;
  }
#pragma unroll
  for (int rr = 0; rr < 2; ++rr) {
    float s = psum[rr];
#pragma unroll
    for (int off = 32; off > 0; off >>= 1) s += __shfl_down(s, off, 64);
    if ((tid & 63) == 0) smf[rr * 4 + (tid >> 6)] = s;
  }
  __syncthreads();
  if (tid < 2) {
    float tot = smf[tid * 4] + smf[tid * 4 + 1] + smf[tid * 4 + 2] + smf[tid * 4 + 3];
    dinv[bx * 2 + tid] = rsqrtf(tot + 1.0f);
  }
}

// ---------------- scale_i8: hq1[h][k] = clamp(rne(h1*dinv[k]*2048)) ----------------
__global__ __launch_bounds__(256) void scale_i8(const unsigned short* __restrict__ h1,
                                                const float* __restrict__ dinv,
                                                char* __restrict__ hq1) {
  size_t e = ((size_t)blockIdx.x * 256 + threadIdx.x) * 16;
  int k = (int)(e & 8191);
  s16x8 v0 = *(const s16x8*)(h1 + e);
  s16x8 v1 = *(const s16x8*)(h1 + e + 8);
  i32x4 o;
#pragma unroll
  for (int q = 0; q < 4; ++q) {
    f32x4 d = *(const f32x4*)(dinv + k + q * 4);
    const s16x8& v = (q < 2) ? v0 : v1;
    int b = (q & 1) * 4;
    int q0 = q_hs(bf2f((unsigned short)v[b + 0]) * d[0]);
    int q1 = q_hs(bf2f((unsigned short)v[b + 1]) * d[1]);
    int q2 = q_hs(bf2f((unsigned short)v[b + 2]) * d[2]);
    int q3 = q_hs(bf2f((unsigned short)v[b + 3]) * d[3]);
    o[q] = (q0 & 0xff) | ((q1 & 0xff) << 8) | ((q2 & 0xff) << 16) | (q3 << 24);
  }
  *(i32x4*)(hq1 + e) = o;
}

// ---------------- big GEMM int8 (split-K=4): P[z] = adjq @ Bq^T partials (i32, exact) ----------------
// BM2=128, BK2=128B, NBUF=3, one barrier/step, 2-deep prefetch, vmcnt(6).
// 16B-granule XOR swizzle; fragments = whole granules (ds_read_b128).
__global__ __launch_bounds__(512) void gemm_big(const char* __restrict__ A,
                                                const char* __restrict__ B,
                                                int* __restrict__ P) {
  __shared__ char lds[3 * BUFB];  // 144 KB
  const int tid = threadIdx.x;
  const int mt = blockIdx.x & 63;
  const int z = blockIdx.x >> 6;
  const int m0 = mt * BM2;

  const int trow = tid >> 3;          // 0..63
  const int srcgr = (tid & 7) ^ (trow & 7);

  const char* Asrc[2];
#pragma unroll
  for (int j = 0; j < 2; ++j)
    Asrc[j] = A + (size_t)(m0 + j * 64 + trow) * KFULL + (size_t)z * KQ + srcgr * 16;
  const char* Bsrc[4];
#pragma unroll
  for (int j = 0; j < 4; ++j)
    Bsrc[j] = B + (size_t)(j * 64 + trow) * KFULL + (size_t)z * KQ + srcgr * 16;

  auto stage = [&](int buf, int t) {  // 6 gload16/thread
    char* L = lds + buf * BUFB;
#pragma unroll
    for (int j = 0; j < 2; ++j)
      gload16(Asrc[j] + (size_t)t * BK2, L + (j * 512 + tid) * 16);
#pragma unroll
    for (int j = 0; j < 4; ++j)
      gload16(Bsrc[j] + (size_t)t * BK2, L + ABYTES + (j * 512 + tid) * 16);
  };

  const int w = tid >> 6, l = tid & 63;
  const int wr = w >> 2, wc = w & 3;
  const int g = l >> 4, lr = l & 15;
  int aoff[4][2], boff[4][2];
#pragma unroll
  for (int m = 0; m < 4; ++m)
#pragma unroll
    for (int ks = 0; ks < 2; ++ks) {
      int r = wr * 64 + m * 16 + lr;
      aoff[m][ks] = r * BK2 + (((ks * 4 + g) ^ (r & 7)) * 16);
    }
#pragma unroll
  for (int n = 0; n < 4; ++n)
#pragma unroll
    for (int ks = 0; ks < 2; ++ks) {
      int r = wc * 64 + n * 16 + lr;
      boff[n][ks] = ABYTES + r * BK2 + (((ks * 4 + g) ^ (r & 7)) * 16);
    }

  i32x4 acc[4][4];
#pragma unroll
  for (int m = 0; m < 4; ++m)
#pragma unroll
    for (int n = 0; n < 4; ++n) {
      i32x4 zz = {0, 0, 0, 0};
      acc[m][n] = zz;
    }

  stage(0, 0);
  stage(1, 1);

  const int nt = KQ / BK2;  // 16
  for (int t = 0; t < nt; ++t) {
    int cur = t % 3;
    if (t + 1 < nt) asm volatile("s_waitcnt vmcnt(6)" ::: "memory");
    else            asm volatile("s_waitcnt vmcnt(0)" ::: "memory");
    asm volatile("s_barrier" ::: "memory");
    __builtin_amdgcn_sched_barrier(0);

    const char* L = lds + cur * BUFB;
    i32x4 af[4][2], bfr[4][2];
#pragma unroll
    for (int m = 0; m < 4; ++m)
#pragma unroll
      for (int ks = 0; ks < 2; ++ks) af[m][ks] = *(const i32x4*)(L + aoff[m][ks]);
#pragma unroll
    for (int n = 0; n < 4; ++n)
#pragma unroll
      for (int ks = 0; ks < 2; ++ks) bfr[n][ks] = *(const i32x4*)(L + boff[n][ks]);

    if (t + 2 < nt) stage((t + 2) % 3, t + 2);

    __builtin_amdgcn_s_setprio(1);
#pragma unroll
    for (int m = 0; m < 4; ++m)
#pragma unroll
      for (int n = 0; n < 4; ++n)
#pragma unroll
        for (int ks = 0; ks < 2; ++ks)
          acc[m][n] = __builtin_amdgcn_mfma_i32_16x16x64_i8(af[m][ks], bfr[n][ks],
                                                            acc[m][n], 0, 0, 0);
    __builtin_amdgcn_s_setprio(0);
  }

  int* Pz = P + (size_t)z * 8192 * 256;
#pragma unroll
  for (int m = 0; m < 4; ++m)
#pragma unroll
    for (int n = 0; n < 4; ++n) {
      int col = wc * 64 + n * 16 + lr;
#pragma unroll
      for (int r = 0; r < 4; ++r) {
        int row = m0 + wr * 64 + m * 16 + g * 4 + r;
        Pz[(size_t)row * 256 + col] = acc[m][n][r];
      }
    }
}

// ---------------- reduce1: hln = LN(GELU(dinv*(ΣPz/Q + dinv*h1col))), bf16 out ----------------
__global__ __launch_bounds__(256) void reduce_ln(const int* __restrict__ P,
                                                 const unsigned short* __restrict__ h1,
                                                 const float* __restrict__ dinv,
                                                 const float* __restrict__ gamma,
                                                 const float* __restrict__ beta,
                                                 unsigned short* __restrict__ hln) {
  const size_t ZSTR = (size_t)8192 * 256;
  int row = blockIdx.x * 4 + (threadIdx.x >> 6);
  int l = threadIdx.x & 63;
  const int* p = P + (size_t)row * 256 + l * 4;
  i32x4 a = *(const i32x4*)p;
  i32x4 b = *(const i32x4*)(p + ZSTR);
  i32x4 c = *(const i32x4*)(p + 2 * ZSTR);
  i32x4 d = *(const i32x4*)(p + 3 * ZSTR);
  float di = dinv[row];
  float gl[4];
  float s = 0.f, q = 0.f;
#pragma unroll
  for (int j = 0; j < 4; ++j) {
    int h = l * 4 + j;
    float agg = (float)(a[j] + b[j] + c[j] + d[j]) * INVQ;
    float hsv = bf2f(h1[(size_t)h * 8192 + row]) * di;  // exact +I term
    float v = (agg + hsv) * di;
    float gv = 0.5f * v * (1.0f + erff(v * 0.70710678118654752440f));
    gl[j] = gv;
    s += gv;
    q += gv * gv;
  }
#pragma unroll
  for (int off = 1; off < 64; off <<= 1) {
    s += __shfl_xor(s, off, 64);
    q += __shfl_xor(q, off, 64);
  }
  float mu = s * (1.0f / 256.0f);
  float var = q * (1.0f / 256.0f) - mu * mu;
  float rs = rsqrtf(fmaxf(var, 0.f) + 1e-6f);
  f32x4 gm = *(const f32x4*)(gamma + l * 4);
  f32x4 bt = *(const f32x4*)(beta + l * 4);
  unsigned short o4[4];
#pragma unroll
  for (int j = 0; j < 4; ++j)
    o4[j] = f2bf((gl[j] - mu) * rs * gm[j] + bt[j]);
  *(unsigned long long*)(hln + (size_t)row * 256 + l * 4) =
      *(const unsigned long long*)o4;
}

// ---------------- reduce2: out fp32 = dinv*(ΣPz/Q + hq2col/2048) ----------------
__global__ __launch_bounds__(256) void reduce_sc(const int* __restrict__ P,
                                                 const char* __restrict__ hq2,
                                                 const float* __restrict__ dinv,
                                                 float* __restrict__ out) {
  const size_t ZSTR = (size_t)8192 * 256;
  int row = blockIdx.x * 4 + (threadIdx.x >> 6);
  int l = threadIdx.x & 63;
  const int* p = P + (size_t)row * 256 + l * 4;
  i32x4 a = *(const i32x4*)p;
  i32x4 b = *(const i32x4*)(p + ZSTR);
  i32x4 c = *(const i32x4*)(p + 2 * ZSTR);
  i32x4 d = *(const i32x4*)(p + 3 * ZSTR);
  float di = dinv[row];
  f32x4 o;
#pragma unroll
  for (int j = 0; j < 4; ++j) {
    int h = l * 4 + j;
    float agg = (float)(a[j] + b[j] + c[j] + d[j]) * INVQ;
    float hsv = (float)((signed char)hq2[(size_t)h * 8192 + row]) * INVSHS;  // +I term
    o[j] = (agg + hsv) * di;
  }
  *(f32x4*)(out + (size_t)row * 256 + l * 4) = o;
}

// ---------------- GEMM6: hq2 = int8((hln @ W2 + b2)^T * dinv[col] * 2048) ----------------
__global__ __launch_bounds__(256) void gemm6_k(const float* __restrict__ W2T,
                                               const unsigned short* __restrict__ hln,
                                               char* __restrict__ hq2,
                                               const float* __restrict__ b2,
                                               const float* __restrict__ dinv) {
  __shared__ unsigned short lds[2 * LDS_TILE];
  gemm_small<false, 6>(blockIdx.x, lds, W2T, hln, hq2, b2, dinv, 256, 8192, 256);
}

// ---------------- launch ----------------
extern "C" void kernel_launch(void* const* d_in, const int* in_sizes, int n_in,
                              void* d_out, int out_size, void* d_ws, size_t ws_size,
                              hipStream_t stream) {
  (void)in_sizes; (void)n_in; (void)out_size; (void)ws_size;
  const float* x     = (const float*)d_in[0];
  const float* adj   = (const float*)d_in[1];
  const float* W1    = (const float*)d_in[2];
  const float* b1    = (const float*)d_in[3];
  const float* W2    = (const float*)d_in[4];
  const float* b2    = (const float*)d_in[5];
  const float* gamma = (const float*)d_in[6];
  const float* beta  = (const float*)d_in[7];
  float* out = (float*)d_out;

  char* ws = (char*)d_ws;
  float* dinv          = (float*)ws;                           // 32 KB
  float* W1T           = (float*)(ws + (64 << 10));            // 512 KB [256][512]
  float* W2T           = (float*)(ws + (640 << 10));           // 256 KB [256][256]
  unsigned short* h1   = (unsigned short*)(ws + (1 << 20));    // 4 MB [256][8192] bf16
  char* hq1            = (char*)(ws + (8 << 20));              // 2 MB [256][8192] int8
  unsigned short* hln  = (unsigned short*)(ws + (12 << 20));   // 4 MB [8192][256] bf16
  char* hq2            = (char*)(ws + (20 << 20));             // 2 MB [256][8192] int8
  int* P               = (int*)(ws + (32 << 20));              // 32 MB [4][8192][256] i32
  char* adjq           = (char*)(ws + (64 << 20));             // 64 MB [8192][8192] int8

  // 0) weight transposes
  transW<<<48, 256, 0, stream>>>(W1, W2, W1T, W2T);
  // 1) gemm3 (h1 bf16) + adj->int8(x127) + rowsum->dinv, fused
  prep<<<4352, 256, 0, stream>>>(adj, x, W1T, b1, adjq, dinv, h1);
  // 2) hq1 = int8(h1 * dinv * 2048)
  scale_i8<<<512, 256, 0, stream>>>(h1, dinv, hq1);
  // 3) P = split-K=4 int32 partials of adjq @ hq1^T
  gemm_big<<<256, 512, 0, stream>>>(adjq, hq1, P);
  // 4) hln = LN(GELU(dinv*(ΣP/Q + dinv*h1)))
  reduce_ln<<<2048, 256, 0, stream>>>(P, h1, dinv, gamma, beta, hln);
  // 5) hq2 = int8((hln @ W2 + b2)^T * dinv * 2048)
  gemm6_k<<<256, 256, 0, stream>>>(W2T, hln, hq2, b2, dinv);
  // 6) P = split-K=4 int32 partials of adjq @ hq2^T
  gemm_big<<<256, 512, 0, stream>>>(adjq, hq2, P);
  // 7) out = dinv*(ΣP/Q + hq2/2048)
  reduce_sc<<<2048, 256, 0, stream>>>(P, hq2, dinv, out);
}

// Round 11
// 161.447 us; speedup vs baseline: 1.4633x; 1.1005x over previous
//
#include <hip/hip_runtime.h>
#include <math.h>

typedef __attribute__((ext_vector_type(4))) float f32x4;
typedef __attribute__((ext_vector_type(8))) short s16x8;
typedef __attribute__((ext_vector_type(4))) short s16x4;
typedef __attribute__((ext_vector_type(2))) int i32x2;
typedef __attribute__((ext_vector_type(4))) int i32x4;

// small-GEMM tile
#define BM 32
#define BN 256
#define BK 64
#define LDS_TILE ((BM + BN) * BK)

// big-GEMM tile (int8)
#define BM2 128
#define BN2 256
#define BK2 128              // elements = bytes per row-chunk
#define KFULL 8192
#define ZSPLIT 4
#define KQ (KFULL / ZSPLIT)  // 2048
#define ABYTES (BM2 * BK2)   // 16384
#define BBYTES (BN2 * BK2)   // 32768
#define BUFB (ABYTES + BBYTES)  // 49152 bytes per buffer

#define SHS 2048.0f
#define SINV16 (64.0f / (127.0f * 2048.0f))  // P16 units -> h-units (layer 1)
#define SINV32 (1.0f / (127.0f * 2048.0f))   // P32 units -> h-units (layer 2)
#define INVSHS (1.0f / 2048.0f)

__device__ __forceinline__ unsigned short f2bf(float f) {
  unsigned int u = __float_as_uint(f);
  u += 0x7fffu + ((u >> 16) & 1u);
  return (unsigned short)(u >> 16);
}
__device__ __forceinline__ float bf2f(unsigned short h) {
  unsigned int u = ((unsigned int)h) << 16;
  return __uint_as_float(u);
}
// round-to-nearest-even float->int for |x| < 2^22 (magic-add trick)
__device__ __forceinline__ int rne_i(float x) {
  return __float_as_int(x + 12582912.0f) - 0x4B400000;
}
__device__ __forceinline__ int q_hs(float v) {
  int q = rne_i(v * SHS);
  return q < -127 ? -127 : (q > 127 ? 127 : q);
}
__device__ __forceinline__ void gload16(const void* g, void* l) {
  __builtin_amdgcn_global_load_lds(
      (const __attribute__((address_space(1))) void*)g,
      (__attribute__((address_space(3))) void*)l, 16, 0, 0);
}

// ---------------- merged weight transposes: W[K][M] -> WT[M][K] fp32 ----------------
__global__ __launch_bounds__(256) void transW(const float* __restrict__ W1,
                                              const float* __restrict__ W2,
                                              float* __restrict__ W1T,
                                              float* __restrict__ W2T) {
  __shared__ float t[64][65];
  int bx = blockIdx.x;
  const float* in;
  float* out;
  int K, M;
  if (bx < 32) { in = W1; out = W1T; K = 512; M = 256; }
  else { bx -= 32; in = W2; out = W2T; K = 256; M = 256; }
  int tiles_m = M >> 6;
  int tk = bx / tiles_m, tm = bx % tiles_m;
  int k0 = tk * 64, m0 = tm * 64;
  int ty = threadIdx.x >> 4, tx = threadIdx.x & 15;
#pragma unroll
  for (int i = 0; i < 4; ++i) {
    f32x4 v = *(const f32x4*)(in + (size_t)(k0 + ty + 16 * i) * M + m0 + tx * 4);
    t[ty + 16 * i][tx * 4 + 0] = v[0];
    t[ty + 16 * i][tx * 4 + 1] = v[1];
    t[ty + 16 * i][tx * 4 + 2] = v[2];
    t[ty + 16 * i][tx * 4 + 3] = v[3];
  }
  __syncthreads();
#pragma unroll
  for (int i = 0; i < 4; ++i) {
    int m = ty + 16 * i;
    f32x4 v = {t[tx * 4 + 0][m], t[tx * 4 + 1][m], t[tx * 4 + 2][m], t[tx * 4 + 3][m]};
    *(f32x4*)(out + (size_t)(m0 + m) * K + k0 + tx * 4) = v;
  }
}

// ---------------- small GEMM (bf16 MFMA): C[M,N] = AT[M,K] * BT[N,K]^T ----------------
// EPI 3: bf16 out = acc + bias[row]                        (gemm3 -> h1)
// EPI 6: int8 out [h][node] + int8 outn [node][h] (transposed via LDS)  (gemm6)
template <bool BF32, int EPI>
__device__ __forceinline__ void gemm_small(int bx, unsigned short* ldsb,
                                           const float* __restrict__ AT,
                                           const void* __restrict__ BTp,
                                           void* __restrict__ outp,
                                           char* __restrict__ outn,
                                           const float* __restrict__ bias,
                                           const float* __restrict__ dinv,
                                           int M, int N, int K) {
  const int tid = threadIdx.x;
  const int m0 = (bx & (M / BM - 1)) * BM;
  const int n0 = (bx / (M / BM)) * BN;
  const int sr = tid >> 3;
  const int sc = (tid & 7) * 8;
  const float* Bf = (const float*)BTp;
  const unsigned short* Bh = (const unsigned short*)BTp;

  f32x4 a_f[2];
  f32x4 b_f[8][2];
  s16x8 b_h[8];

  auto stage_load = [&](int k0) {
    const float* pa = AT + (size_t)(m0 + sr) * K + k0 + sc;
    a_f[0] = *(const f32x4*)(pa);
    a_f[1] = *(const f32x4*)(pa + 4);
#pragma unroll
    for (int it = 0; it < 8; ++it) {
      int n = n0 + it * 32 + sr;
      if (BF32) {
        const float* p = Bf + (size_t)n * K + k0 + sc;
        b_f[it][0] = *(const f32x4*)(p);
        b_f[it][1] = *(const f32x4*)(p + 4);
      } else {
        b_h[it] = *(const s16x8*)(Bh + (size_t)n * K + k0 + sc);
      }
    }
  };

  auto stage_write = [&](int buf) {
    unsigned short* L = ldsb + buf * LDS_TILE;
    {
      s16x8 v;
#pragma unroll
      for (int j = 0; j < 8; ++j) v[j] = (short)f2bf(j < 4 ? a_f[0][j] : a_f[1][j - 4]);
      int idx = (sr * BK + sc) ^ ((sr & 7) << 3);
      *(s16x8*)(L + idx) = v;
    }
#pragma unroll
    for (int it = 0; it < 8; ++it) {
      int r = it * 32 + sr;
      s16x8 w;
      if (BF32) {
#pragma unroll
        for (int j = 0; j < 8; ++j)
          w[j] = (short)f2bf(j < 4 ? b_f[it][0][j] : b_f[it][1][j - 4]);
      } else {
        w = b_h[it];
      }
      int idx = BM * BK + ((r * BK + sc) ^ ((r & 7) << 3));
      *(s16x8*)(L + idx) = w;
    }
  };

  const int lane = tid & 63;
  const int wv = tid >> 6;
  const int g = lane >> 4, lr = lane & 15;

  int aidx[2][2], bidx[4][2];
#pragma unroll
  for (int m = 0; m < 2; ++m)
#pragma unroll
    for (int ks = 0; ks < 2; ++ks) {
      int r = m * 16 + lr;
      aidx[m][ks] = (r * BK + ks * 32 + g * 8) ^ ((r & 7) << 3);
    }
#pragma unroll
  for (int n = 0; n < 4; ++n)
#pragma unroll
    for (int ks = 0; ks < 2; ++ks) {
      int r = wv * 64 + n * 16 + lr;
      bidx[n][ks] = BM * BK + ((r * BK + ks * 32 + g * 8) ^ ((r & 7) << 3));
    }

  f32x4 acc[2][4];
#pragma unroll
  for (int m = 0; m < 2; ++m)
#pragma unroll
    for (int n = 0; n < 4; ++n) {
      f32x4 z = {0.f, 0.f, 0.f, 0.f};
      acc[m][n] = z;
    }

  auto compute = [&](int buf) {
    const unsigned short* L = ldsb + buf * LDS_TILE;
    s16x8 af[2][2], bfr[4][2];
#pragma unroll
    for (int m = 0; m < 2; ++m)
#pragma unroll
      for (int ks = 0; ks < 2; ++ks) af[m][ks] = *(const s16x8*)(L + aidx[m][ks]);
#pragma unroll
    for (int n = 0; n < 4; ++n)
#pragma unroll
      for (int ks = 0; ks < 2; ++ks) bfr[n][ks] = *(const s16x8*)(L + bidx[n][ks]);
#pragma unroll
    for (int m = 0; m < 2; ++m)
#pragma unroll
      for (int n = 0; n < 4; ++n)
#pragma unroll
        for (int ks = 0; ks < 2; ++ks)
          acc[m][n] = __builtin_amdgcn_mfma_f32_16x16x32_bf16(af[m][ks], bfr[n][ks],
                                                              acc[m][n], 0, 0, 0);
  };

  stage_load(0);
  stage_write(0);
  __syncthreads();
  int cur = 0;
  const int nt = K / BK;
  for (int t = 0; t < nt; ++t) {
    if (t + 1 < nt) stage_load((t + 1) * BK);
    compute(cur);
    if (t + 1 < nt) {
      stage_write(cur ^ 1);
      __syncthreads();
      cur ^= 1;
    }
  }

  if constexpr (EPI == 3) {
#pragma unroll
    for (int m = 0; m < 2; ++m)
#pragma unroll
      for (int n = 0; n < 4; ++n) {
        int col = n0 + wv * 64 + n * 16 + lr;
#pragma unroll
        for (int r = 0; r < 4; ++r) {
          int row = m0 + m * 16 + g * 4 + r;
          ((unsigned short*)outp)[(size_t)row * N + col] = f2bf(acc[m][n][r] + bias[row]);
        }
      }
  } else {
    // EPI 6: quantize; write [h][node] scalar + [node][h] via LDS T2[256][48]
    __syncthreads();
    char* T2 = (char*)ldsb;
#pragma unroll
    for (int m = 0; m < 2; ++m)
#pragma unroll
      for (int n = 0; n < 4; ++n) {
        int cl = wv * 64 + n * 16 + lr;
        float dv = dinv[n0 + cl];
#pragma unroll
        for (int r = 0; r < 4; ++r) {
          int rl = m * 16 + g * 4 + r;
          int q = q_hs((acc[m][n][r] + bias[m0 + rl]) * dv);
          T2[cl * 48 + rl] = (char)q;
          ((char*)outp)[(size_t)(m0 + rl) * N + n0 + cl] = (char)q;
        }
      }
    __syncthreads();
#pragma unroll
    for (int h = 0; h < 2; ++h) {
      i32x4 vv = *(const i32x4*)(T2 + tid * 48 + h * 16);
      *(i32x4*)(outn + (size_t)(n0 + tid) * 256 + m0 + h * 16) = vv;
    }
  }
}

// ---------------- prep: gemm3 blocks [0,256) + adj conv/rowsum blocks [256,4352) ----------------
__global__ __launch_bounds__(256) void prep(const float* __restrict__ adj,
                                            const float* __restrict__ x,
                                            const float* __restrict__ W1T,
                                            const float* __restrict__ b1,
                                            char* __restrict__ adjq,
                                            float* __restrict__ dinv,
                                            unsigned short* __restrict__ h1) {
  __shared__ unsigned short lds[2 * LDS_TILE];
  int bx = blockIdx.x;
  if (bx < 256) {
    gemm_small<true, 3>(bx, lds, W1T, x, h1, nullptr, b1, nullptr, 256, 8192, 512);
    return;
  }
  bx -= 256;
  float* smf = (float*)lds;
  const int tid = threadIdx.x;
  float psum[2];
#pragma unroll
  for (int rr = 0; rr < 2; ++rr) {
    int row = bx * 2 + rr;
    const float* src = adj + (size_t)row * 8192;
    char* dst = adjq + (size_t)row * 8192;
    float s = 0.f;
    for (int c = tid * 8; c < 8192; c += 2048) {
      f32x4 v0 = __builtin_nontemporal_load((const f32x4*)(src + c));
      f32x4 v1 = __builtin_nontemporal_load((const f32x4*)(src + c + 4));
      s += v0[0] + v0[1] + v0[2] + v0[3] + v1[0] + v1[1] + v1[2] + v1[3];
      // no +I fold: identity term added exactly in the reduce kernels
      i32x2 o;
      o[0] = (rne_i(v0[0] * 127.f) & 0xff) | ((rne_i(v0[1] * 127.f) & 0xff) << 8) |
             ((rne_i(v0[2] * 127.f) & 0xff) << 16) | (rne_i(v0[3] * 127.f) << 24);
      o[1] = (rne_i(v1[0] * 127.f) & 0xff) | ((rne_i(v1[1] * 127.f) & 0xff) << 8) |
             ((rne_i(v1[2] * 127.f) & 0xff) << 16) | (rne_i(v1[3] * 127.f) << 24);
      *(i32x2*)(dst + c) = o;
    }
    psum[rr] = s;
  }
#pragma unroll
  for (int rr = 0; rr < 2; ++rr) {
    float s = psum[rr];
#pragma unroll
    for (int off = 32; off > 0; off >>= 1) s += __shfl_down(s, off, 64);
    if ((tid & 63) == 0) smf[rr * 4 + (tid >> 6)] = s;
  }
  __syncthreads();
  if (tid < 2) {
    float tot = smf[tid * 4] + smf[tid * 4 + 1] + smf[tid * 4 + 2] + smf[tid * 4 + 3];
    dinv[bx * 2 + tid] = rsqrtf(tot + 1.0f);
  }
}

// ---------------- scale_tr: hq1[h][k]=q(h1*dinv[k]) + transposed hq1n[k][h] ----------------
__global__ __launch_bounds__(256) void scale_tr(const unsigned short* __restrict__ h1,
                                                const float* __restrict__ dinv,
                                                char* __restrict__ hq1,
                                                char* __restrict__ hq1n) {
  __shared__ char Tq[64][80];  // [node_local][h_local pad]
  int nt_ = blockIdx.x >> 2, ht = blockIdx.x & 3;
  int n0 = nt_ * 64, h0 = ht * 64;
  const int tid = threadIdx.x;
  const int c8 = (tid & 7) * 8;
  f32x4 d0 = *(const f32x4*)(dinv + n0 + c8);
  f32x4 d1 = *(const f32x4*)(dinv + n0 + c8 + 4);
#pragma unroll
  for (int it = 0; it < 2; ++it) {
    int hh = (tid >> 3) + it * 32;
    s16x8 v = *(const s16x8*)(h1 + (size_t)(h0 + hh) * 8192 + n0 + c8);
    unsigned int lo = 0, hi = 0;
#pragma unroll
    for (int j = 0; j < 8; ++j) {
      float dv = (j < 4) ? d0[j] : d1[j - 4];
      int q = q_hs(bf2f((unsigned short)v[j]) * dv);
      Tq[c8 + j][hh] = (char)q;
      if (j < 4) lo |= ((unsigned int)(q & 0xff)) << (8 * j);
      else       hi |= ((unsigned int)(q & 0xff)) << (8 * (j - 4));
    }
    i32x2 o;
    o[0] = (int)lo;
    o[1] = (int)hi;
    *(i32x2*)(hq1 + (size_t)(h0 + hh) * 8192 + n0 + c8) = o;
  }
  __syncthreads();
  int node = tid >> 2, h16 = (tid & 3) * 16;
  i32x4 vv = *(const i32x4*)(&Tq[node][h16]);
  *(i32x4*)(hq1n + (size_t)(n0 + node) * 256 + h0 + h16) = vv;
}

// ---------------- big GEMM int8 (split-K=4): partials of adjq @ Bq^T ----------------
// P16OUT: int16 partials (acc+32)>>6 via LDS-transpose (layer 1 only — zero-col-mean B).
// else:   int32 partials direct store (layer 2 — col means make partials ~3.5M std).
template <bool P16OUT>
__global__ __launch_bounds__(512) void gemm_big(const char* __restrict__ A,
                                                const char* __restrict__ B,
                                                void* __restrict__ Pout) {
  __shared__ char lds[3 * BUFB];  // 144 KB
  const int tid = threadIdx.x;
  const int mt = blockIdx.x & 63;
  const int z = blockIdx.x >> 6;
  const int m0 = mt * BM2;

  const int trow = tid >> 3;          // 0..63
  const int srcgr = (tid & 7) ^ (trow & 7);

  const char* Asrc[2];
#pragma unroll
  for (int j = 0; j < 2; ++j)
    Asrc[j] = A + (size_t)(m0 + j * 64 + trow) * KFULL + (size_t)z * KQ + srcgr * 16;
  const char* Bsrc[4];
#pragma unroll
  for (int j = 0; j < 4; ++j)
    Bsrc[j] = B + (size_t)(j * 64 + trow) * KFULL + (size_t)z * KQ + srcgr * 16;

  auto stage = [&](int buf, int t) {  // 6 gload16/thread
    char* L = lds + buf * BUFB;
#pragma unroll
    for (int j = 0; j < 2; ++j)
      gload16(Asrc[j] + (size_t)t * BK2, L + (j * 512 + tid) * 16);
#pragma unroll
    for (int j = 0; j < 4; ++j)
      gload16(Bsrc[j] + (size_t)t * BK2, L + ABYTES + (j * 512 + tid) * 16);
  };

  const int w = tid >> 6, l = tid & 63;
  const int wr = w >> 2, wc = w & 3;
  const int g = l >> 4, lr = l & 15;
  int aoff[4][2], boff[4][2];
#pragma unroll
  for (int m = 0; m < 4; ++m)
#pragma unroll
    for (int ks = 0; ks < 2; ++ks) {
      int r = wr * 64 + m * 16 + lr;
      aoff[m][ks] = r * BK2 + (((ks * 4 + g) ^ (r & 7)) * 16);
    }
#pragma unroll
  for (int n = 0; n < 4; ++n)
#pragma unroll
    for (int ks = 0; ks < 2; ++ks) {
      int r = wc * 64 + n * 16 + lr;
      boff[n][ks] = ABYTES + r * BK2 + (((ks * 4 + g) ^ (r & 7)) * 16);
    }

  i32x4 acc[4][4];
#pragma unroll
  for (int m = 0; m < 4; ++m)
#pragma unroll
    for (int n = 0; n < 4; ++n) {
      i32x4 zz = {0, 0, 0, 0};
      acc[m][n] = zz;
    }

  stage(0, 0);
  stage(1, 1);

  const int nt = KQ / BK2;  // 16
  for (int t = 0; t < nt; ++t) {
    int cur = t % 3;
    if (t + 1 < nt) asm volatile("s_waitcnt vmcnt(6)" ::: "memory");
    else            asm volatile("s_waitcnt vmcnt(0)" ::: "memory");
    asm volatile("s_barrier" ::: "memory");
    __builtin_amdgcn_sched_barrier(0);

    const char* L = lds + cur * BUFB;
    i32x4 af[4][2], bfr[4][2];
#pragma unroll
    for (int m = 0; m < 4; ++m)
#pragma unroll
      for (int ks = 0; ks < 2; ++ks) af[m][ks] = *(const i32x4*)(L + aoff[m][ks]);
#pragma unroll
    for (int n = 0; n < 4; ++n)
#pragma unroll
      for (int ks = 0; ks < 2; ++ks) bfr[n][ks] = *(const i32x4*)(L + boff[n][ks]);

    if (t + 2 < nt) stage((t + 2) % 3, t + 2);

    __builtin_amdgcn_s_setprio(1);
#pragma unroll
    for (int m = 0; m < 4; ++m)
#pragma unroll
      for (int n = 0; n < 4; ++n)
#pragma unroll
        for (int ks = 0; ks < 2; ++ks)
          acc[m][n] = __builtin_amdgcn_mfma_i32_16x16x64_i8(af[m][ks], bfr[n][ks],
                                                            acc[m][n], 0, 0, 0);
    __builtin_amdgcn_s_setprio(0);
  }

  if constexpr (!P16OUT) {
    // layer 2: int32 direct stores (R9-proven)
    int* Pz = (int*)Pout + (size_t)z * 8192 * 256;
#pragma unroll
    for (int m = 0; m < 4; ++m)
#pragma unroll
      for (int n = 0; n < 4; ++n) {
        int col = wc * 64 + n * 16 + lr;
#pragma unroll
        for (int r = 0; r < 4; ++r) {
          int row = m0 + wr * 64 + m * 16 + g * 4 + r;
          Pz[(size_t)row * 256 + col] = acc[m][n][r];
        }
      }
  } else {
    // layer 1: int16 partials via LDS transpose [128][264], coalesced 16B stores
    __syncthreads();
    unsigned short* Tp = (unsigned short*)lds;
#pragma unroll
    for (int m = 0; m < 4; ++m)
#pragma unroll
      for (int n = 0; n < 4; ++n) {
        int cl = wc * 64 + n * 16 + lr;
#pragma unroll
        for (int r = 0; r < 4; ++r) {
          int rl = wr * 64 + m * 16 + g * 4 + r;
          int v = (acc[m][n][r] + 32) >> 6;
          v = v < -32768 ? -32768 : (v > 32767 ? 32767 : v);
          Tp[rl * 264 + cl] = (unsigned short)(short)v;
        }
      }
    __syncthreads();
    short* Pz = (short*)Pout + (size_t)z * 8192 * 256 + (size_t)m0 * 256;
#pragma unroll
    for (int pass = 0; pass < 8; ++pass) {
      int c = pass * 512 + tid;            // 16B chunk id
      int r = c >> 5, off = (c & 31) * 8;  // in shorts
      s16x8 v = *(const s16x8*)(Tp + r * 264 + off);
      *(s16x8*)(Pz + (size_t)c * 8) = v;
    }
  }
}

// ---------------- reduce1: hln = LN(GELU(dinv*(ΣP16*SINV16 + hq1n/2048))), bf16 ----------------
__global__ __launch_bounds__(256) void reduce_ln(const short* __restrict__ P16,
                                                 const char* __restrict__ hq1n,
                                                 const float* __restrict__ dinv,
                                                 const float* __restrict__ gamma,
                                                 const float* __restrict__ beta,
                                                 unsigned short* __restrict__ hln) {
  const size_t ZSTR = (size_t)8192 * 256;
  int row = blockIdx.x * 4 + (threadIdx.x >> 6);
  int l = threadIdx.x & 63;
  const short* p = P16 + (size_t)row * 256 + l * 4;
  s16x4 a = *(const s16x4*)p;
  s16x4 b = *(const s16x4*)(p + ZSTR);
  s16x4 c = *(const s16x4*)(p + 2 * ZSTR);
  s16x4 d = *(const s16x4*)(p + 3 * ZSTR);
  int q4 = *(const int*)(hq1n + (size_t)row * 256 + l * 4);
  float di = dinv[row];
  float gl[4];
  float s = 0.f, q = 0.f;
#pragma unroll
  for (int j = 0; j < 4; ++j) {
    float agg = (float)((int)a[j] + b[j] + c[j] + d[j]) * SINV16;
    float hsv = (float)((signed char)(q4 >> (8 * j))) * INVSHS;  // +I term
    float v = (agg + hsv) * di;
    float gv = 0.5f * v * (1.0f + erff(v * 0.70710678118654752440f));
    gl[j] = gv;
    s += gv;
    q += gv * gv;
  }
#pragma unroll
  for (int off = 1; off < 64; off <<= 1) {
    s += __shfl_xor(s, off, 64);
    q += __shfl_xor(q, off, 64);
  }
  float mu = s * (1.0f / 256.0f);
  float var = q * (1.0f / 256.0f) - mu * mu;
  float rs = rsqrtf(fmaxf(var, 0.f) + 1e-6f);
  f32x4 gm = *(const f32x4*)(gamma + l * 4);
  f32x4 bt = *(const f32x4*)(beta + l * 4);
  unsigned short o4[4];
#pragma unroll
  for (int j = 0; j < 4; ++j)
    o4[j] = f2bf((gl[j] - mu) * rs * gm[j] + bt[j]);
  *(unsigned long long*)(hln + (size_t)row * 256 + l * 4) =
      *(const unsigned long long*)o4;
}

// ---------------- reduce2: out fp32 = dinv*(ΣP32*SINV32 + hq2n/2048) ----------------
__global__ __launch_bounds__(256) void reduce_sc(const int* __restrict__ P32,
                                                 const char* __restrict__ hq2n,
                                                 const float* __restrict__ dinv,
                                                 float* __restrict__ out) {
  const size_t ZSTR = (size_t)8192 * 256;
  int row = blockIdx.x * 4 + (threadIdx.x >> 6);
  int l = threadIdx.x & 63;
  const int* p = P32 + (size_t)row * 256 + l * 4;
  i32x4 a = *(const i32x4*)p;
  i32x4 b = *(const i32x4*)(p + ZSTR);
  i32x4 c = *(const i32x4*)(p + 2 * ZSTR);
  i32x4 d = *(const i32x4*)(p + 3 * ZSTR);
  int q4 = *(const int*)(hq2n + (size_t)row * 256 + l * 4);
  float di = dinv[row];
  f32x4 o;
#pragma unroll
  for (int j = 0; j < 4; ++j) {
    float agg = (float)(a[j] + b[j] + c[j] + d[j]) * SINV32;
    float hsv = (float)((signed char)(q4 >> (8 * j))) * INVSHS;
    o[j] = (agg + hsv) * di;
  }
  *(f32x4*)(out + (size_t)row * 256 + l * 4) = o;
}

// ---------------- GEMM6: hq2 [h][node] + hq2n [node][h] ----------------
__global__ __launch_bounds__(256) void gemm6_k(const float* __restrict__ W2T,
                                               const unsigned short* __restrict__ hln,
                                               char* __restrict__ hq2,
                                               char* __restrict__ hq2n,
                                               const float* __restrict__ b2,
                                               const float* __restrict__ dinv) {
  __shared__ unsigned short lds[2 * LDS_TILE];
  gemm_small<false, 6>(blockIdx.x, lds, W2T, hln, hq2, hq2n, b2, dinv, 256, 8192, 256);
}

// ---------------- launch ----------------
extern "C" void kernel_launch(void* const* d_in, const int* in_sizes, int n_in,
                              void* d_out, int out_size, void* d_ws, size_t ws_size,
                              hipStream_t stream) {
  (void)in_sizes; (void)n_in; (void)out_size; (void)ws_size;
  const float* x     = (const float*)d_in[0];
  const float* adj   = (const float*)d_in[1];
  const float* W1    = (const float*)d_in[2];
  const float* b1    = (const float*)d_in[3];
  const float* W2    = (const float*)d_in[4];
  const float* b2    = (const float*)d_in[5];
  const float* gamma = (const float*)d_in[6];
  const float* beta  = (const float*)d_in[7];
  float* out = (float*)d_out;

  char* ws = (char*)d_ws;
  float* dinv          = (float*)ws;                           // 32 KB
  float* W1T           = (float*)(ws + (64 << 10));            // 512 KB [256][512]
  float* W2T           = (float*)(ws + (640 << 10));           // 256 KB [256][256]
  unsigned short* h1   = (unsigned short*)(ws + (1 << 20));    // 4 MB [256][8192] bf16
  char* hq1            = (char*)(ws + (8 << 20));              // 2 MB [256][8192] int8
  char* hq1n           = (char*)(ws + (10 << 20));             // 2 MB [8192][256] int8
  unsigned short* hln  = (unsigned short*)(ws + (14 << 20));   // 4 MB [8192][256] bf16
  char* hq2            = (char*)(ws + (20 << 20));             // 2 MB [256][8192] int8
  char* hq2n           = (char*)(ws + (24 << 20));             // 2 MB [8192][256] int8
  void* P              = (void*)(ws + (32 << 20));             // 32 MB: [4][8192][256] i16 (L1) / i32 (L2)
  char* adjq           = (char*)(ws + (64 << 20));             // 64 MB [8192][8192] int8

  // 0) weight transposes
  transW<<<48, 256, 0, stream>>>(W1, W2, W1T, W2T);
  // 1) gemm3 (h1 bf16) + adj->int8(x127) + rowsum->dinv, fused
  prep<<<4352, 256, 0, stream>>>(adj, x, W1T, b1, adjq, dinv, h1);
  // 2) hq1 = int8(h1 * dinv * 2048), both layouts
  scale_tr<<<512, 256, 0, stream>>>(h1, dinv, hq1, hq1n);
  // 3) P(i16) = split-K=4 int16 partials of adjq @ hq1^T  (layer-1: zero-col-mean B, safe)
  gemm_big<true><<<256, 512, 0, stream>>>(adjq, hq1, P);
  // 4) hln = LN(GELU(dinv*(ΣP + hs1)))
  reduce_ln<<<2048, 256, 0, stream>>>((const short*)P, hq1n, dinv, gamma, beta, hln);
  // 5) hq2 = int8((hln @ W2 + b2)^T * dinv * 2048), both layouts
  gemm6_k<<<256, 256, 0, stream>>>(W2T, hln, hq2, hq2n, b2, dinv);
  // 6) P(i32) = split-K=4 int32 partials of adjq @ hq2^T  (layer-2: col-mean-dominated, needs i32)
  gemm_big<false><<<256, 512, 0, stream>>>(adjq, hq2, P);
  // 7) out = dinv*(ΣP + hs2)
  reduce_sc<<<2048, 256, 0, stream>>>((const int*)P, hq2n, dinv, out);
}